// Round 3
// baseline (963.873 us; speedup 1.0000x reference)
//
#include <hip/hip_runtime.h>
#include <math.h>

#define BATCH 256
#define SEQ 512
#define SDS 54            // floats per (b,t) record: dt[6] hc[6] hs[6] Cc[18] term[18]
#define PI_F 3.14159265358979323846f

// ---- cross-lane helpers -----------------------------------------------------
template<int CTRL>
__device__ __forceinline__ float fdpp(float v) {
    return __int_as_float(__builtin_amdgcn_mov_dpp(__float_as_int(v), CTRL, 0xF, 0xF, true));
}
template<int L>
__device__ __forceinline__ float rdl(float v) {
    return __int_as_float(__builtin_amdgcn_readlane(__float_as_int(v), L));
}
template<int M>
__device__ __forceinline__ float shxm(float v) {
    if constexpr (M == 1)       return fdpp<0xB1>(v);
    else if constexpr (M == 2)  return fdpp<0x4E>(v);
    else if constexpr (M == 8)  return fdpp<0x128>(v);
    else if constexpr (M == 32) return __shfl_xor(v, 32, 64);
    else return __int_as_float(__builtin_amdgcn_ds_swizzle(__float_as_int(v), (M << 10) | 0x1F));
}
// full 64-lane sum (uniform result): DPP row_ror rotate-adds + readlane combine
__device__ __forceinline__ float redsum64(float v) {
    v += fdpp<0x128>(v);
    v += fdpp<0x124>(v);
    v += fdpp<0x122>(v);
    v += fdpp<0x121>(v);
    return (rdl<0>(v) + rdl<16>(v)) + (rdl<32>(v) + rdl<48>(v));
}
__device__ __forceinline__ float xorf(float v, int m) {
    return __int_as_float(__float_as_int(v) ^ m);
}
// Same-wave LDS visibility: drain lgkmcnt only (vmcnt(63) expcnt(7) lgkmcnt(0)
// = 0xC07F in gfx9 encoding). No s_barrier — single-wave workgroup. The
// sched_barriers pin the ds_write before / ds_reads after the hardware wait.
__device__ __forceinline__ void wave_lds_sync() {
    __builtin_amdgcn_sched_barrier(0);
    __builtin_amdgcn_s_waitcnt(0xC07F);
    __builtin_amdgcn_sched_barrier(0);
}
// QSVT per-degree CNOT-block permutation (GF(2)-linear) — verified R1-R6
__device__ __forceinline__ int permf(int x) {
    const int cs[11] = {0,1,2,3,4,5,5,4,3,2,1};
    const int ts[11] = {1,2,3,4,5,0,4,3,2,1,0};
#pragma unroll
    for (int k = 10; k >= 0; k--) {
        int cb = (x >> (5 - cs[k])) & 1;
        x ^= cb << (5 - ts[k]);
    }
    return x;
}
__device__ __forceinline__ void cmul4(const float* c,
    float vr, float vi, float ar, float ai, float br, float bi, float cr, float ci,
    float& nr, float& ni) {
    nr = c[0]*vr - c[1]*vi + c[2]*ar - c[3]*ai + c[4]*br - c[5]*bi + c[6]*cr - c[7]*ci;
    ni = c[0]*vi + c[1]*vr + c[2]*ai + c[3]*ar + c[4]*bi + c[5]*br + c[6]*ci + c[7]*cr;
}
__device__ __forceinline__ void ringapply(const float* rc,
    float vr, float vi, float br, float bi, float cr, float ci, float dr, float di,
    float& nr, float& ni) {
    nr = rc[0]*vr - rc[1]*bi - rc[2]*ci + rc[3]*dr;
    ni = rc[0]*vi + rc[1]*br + rc[2]*cr + rc[3]*di;
}

// ---------------------------------------------------------------------------
// prep_kernel. NOTE: stores 0.5*cos, 0.5*sin in rec[6..17] (folds the 0.5 of
// sincos(h/2) into the h-recurrence), compensated by 2x on Cc rows 0-5 and
// 12-17 (the px and h' output coefficients). Y coefficients (rows 6-11) and
// the post_kernel formulas are unchanged.
// ---------------------------------------------------------------------------
__global__ __launch_bounds__(256) void prep_kernel(
    const float* __restrict__ angles, const float* __restrict__ Wx,
    const float* __restrict__ Wdt, const float* __restrict__ bdt,
    const float* __restrict__ D, const float* __restrict__ Wc,
    float* __restrict__ sd)
{
    int gid = blockIdx.x * blockDim.x + threadIdx.x;
    if (gid >= BATCH * SEQ) return;
    const float* a = angles + (size_t)gid * 6;
    float ang[6];
#pragma unroll
    for (int i = 0; i < 6; i++) ang[i] = a[i];
    float dtr[3];
#pragma unroll
    for (int r = 0; r < 3; r++) {
        float s = 0.f;
#pragma unroll
        for (int k = 0; k < 6; k++) s += ang[k] * Wx[r * 6 + k];
        dtr[r] = s;
    }
    float* rec = sd + (size_t)gid * SDS;
    float dtv[6];
#pragma unroll
    for (int i = 0; i < 6; i++) {
        float x = bdt[i];
#pragma unroll
        for (int r = 0; r < 3; r++) x += dtr[r] * Wdt[i * 3 + r];
        float sp = (x > 15.f) ? x : log1pf(expf(x));
        dtv[i] = tanhf(sp) * PI_F;
        rec[i] = dtv[i];
        float th = ang[i] * dtv[i];
        rec[6 + i]  = 0.5f * cosf(th);
        rec[12 + i] = 0.5f * sinf(th);
    }
    float C[6];
#pragma unroll
    for (int i = 0; i < 6; i++) {
        float s = 0.f;
#pragma unroll
        for (int k = 0; k < 6; k++) s += ang[k] * Wx[(9 + i) * 6 + k];
        C[i] = s;
    }
#pragma unroll
    for (int j = 0; j < 18; j++) {
        float s = 0.f;
#pragma unroll
        for (int i = 0; i < 6; i++) s += C[i] * Wc[j * 6 + i];
        rec[18 + j] = (j < 6 || j >= 12) ? 2.f * s : s;
        rec[36 + j] = D[j] * ang[j % 6];
    }
}

// ---------------------------------------------------------------------------
// umat_kernel: U[a][col] for the fixed 2-layer ansatz (R2-verified gate chain).
// ---------------------------------------------------------------------------
__global__ __launch_bounds__(64) void umat_kernel(const float* __restrict__ cp,
                                                  float2* __restrict__ um)
{
    const int lane = threadIdx.x;
    const int col = blockIdx.x;
    int bitv[6];
#pragma unroll
    for (int i = 0; i < 6; i++) bitv[i] = (lane >> (5 - i)) & 1;

    float qc[2][3][8], rc[2][6][4];
#pragma unroll
    for (int l = 0; l < 2; l++) {
        float g00r[6], g00i[6], g01r[6], g01i[6], g10r[6], g10i[6], g11r[6], g11i[6];
#pragma unroll
        for (int i = 0; i < 6; i++) {
            float ax = cp[l * 30 + i * 3 + 0];
            float ay = cp[l * 30 + i * 3 + 1];
            float az = cp[l * 30 + i * 3 + 2];
            float ca = cosf(0.5f * ax), sa = sinf(0.5f * ax);
            float cb = cosf(0.5f * ay), sb = sinf(0.5f * ay);
            float cg = cosf(0.5f * az), sg = sinf(0.5f * az);
            float m00r = cb * ca, m00i =  sb * sa;
            float m01r = -sb * ca, m01i = -cb * sa;
            float m10r =  sb * ca, m10i = -cb * sa;
            float m11r =  cb * ca, m11i = -sb * sa;
            g00r[i] = cg * m00r + sg * m00i; g00i[i] = cg * m00i - sg * m00r;
            g01r[i] = cg * m01r + sg * m01i; g01i[i] = cg * m01i - sg * m01r;
            g10r[i] = cg * m10r - sg * m10i; g10i[i] = cg * m10i + sg * m10r;
            g11r[i] = cg * m11r - sg * m11i; g11i[i] = cg * m11i + sg * m11r;
        }
#pragma unroll
        for (int pp = 0; pp < 3; pp++) {
            int aq = 2 * pp, bq = 2 * pp + 1;
            float dar = bitv[aq] ? g11r[aq] : g00r[aq], dai = bitv[aq] ? g11i[aq] : g00i[aq];
            float oar = bitv[aq] ? g10r[aq] : g01r[aq], oai = bitv[aq] ? g10i[aq] : g01i[aq];
            float dbr = bitv[bq] ? g11r[bq] : g00r[bq], dbi = bitv[bq] ? g11i[bq] : g00i[bq];
            float obr = bitv[bq] ? g10r[bq] : g01r[bq], obi = bitv[bq] ? g10i[bq] : g01i[bq];
            qc[l][pp][0] = dar * dbr - dai * dbi;  qc[l][pp][1] = dar * dbi + dai * dbr;
            qc[l][pp][2] = oar * dbr - oai * dbi;  qc[l][pp][3] = oar * dbi + oai * dbr;
            qc[l][pp][4] = dar * obr - dai * obi;  qc[l][pp][5] = dar * obi + dai * obr;
            qc[l][pp][6] = oar * obr - oai * obi;  qc[l][pp][7] = oar * obi + oai * obr;
        }
        const int Aq[6] = {0, 2, 4, 5, 3, 1};
        const int Bq[6] = {1, 3, 5, 4, 2, 0};
#pragma unroll
        for (int o = 0; o < 6; o++) {
            float tha = (o < 3) ? cp[l * 30 + 18 + 2 * o]     : cp[l * 30 + 24 + 2 * (o - 3)];
            float thb = (o < 3) ? cp[l * 30 + 18 + 2 * o + 1] : cp[l * 30 + 24 + 2 * (o - 3) + 1];
            float ca = cosf(0.5f * tha), sa = sinf(0.5f * tha);
            float cb = cosf(0.5f * thb), sb = sinf(0.5f * thb);
            int ba = bitv[Aq[o]], bb = bitv[Bq[o]];
            float mx0 = ba ? ca : 1.f, sae = ba ? sa : 0.f;
            float ny0 = bb ? cb : 1.f, sbe = bb ? sb : 0.f;
            rc[l][o][0] = ny0 * mx0; rc[l][o][1] = -ny0 * sae;
            rc[l][o][2] = -mx0 * sbe; rc[l][o][3] = -sae * sbe;
        }
    }

    float re = (lane == col) ? 1.f : 0.f;
    float im = 0.f;
    auto p1q = [&](int mi, int mj, const float* c) {
        float ar = __shfl_xor(re, mi, 64), ai = __shfl_xor(im, mi, 64);
        float br = __shfl_xor(re, mj, 64), bi = __shfl_xor(im, mj, 64);
        float cr = __shfl_xor(re, mi | mj, 64), ci = __shfl_xor(im, mi | mj, 64);
        float nr, ni;
        cmul4(c, re, im, ar, ai, br, bi, cr, ci, nr, ni);
        re = nr; im = ni;
    };
    auto rng = [&](int mb, int mc, const float* c) {
        float br = __shfl_xor(re, mb, 64), bi = __shfl_xor(im, mb, 64);
        float cr = __shfl_xor(re, mc, 64), ci = __shfl_xor(im, mc, 64);
        float dr = __shfl_xor(re, mb | mc, 64), di = __shfl_xor(im, mb | mc, 64);
        float nr, ni;
        ringapply(c, re, im, br, bi, cr, ci, dr, di, nr, ni);
        re = nr; im = ni;
    };
#pragma unroll
    for (int l = 0; l < 2; l++) {
        p1q(32, 16, qc[l][0]);
        p1q(8, 4, qc[l][1]);
        p1q(2, 1, qc[l][2]);
        rng(16, 8, rc[l][0]);
        rng(4, 2, rc[l][1]);
        rng(1, 32, rc[l][2]);
        rng(2, 4, rc[l][3]);
        rng(8, 16, rc[l][4]);
        rng(32, 1, rc[l][5]);
    }
    um[(size_t)lane * 64 + col] = make_float2(re, im);
}

// ---------------------------------------------------------------------------
// step_kernel v3: ONE wave per batch element (grid 256 x 64). Zero barriers.
// The wave holds its full U row (64 float2 in VGPRs); p is broadcast through
// a 512B LDS buffer (ds_write + lgkmcnt(0) + uniform-address ds_read_b128 —
// broadcast reads, conflict-free, no readlane SGPR hazards). Z,X via WHT
// butterflies, Y via 6 in-wave signed correlations on psi:
//   Y_q = sum_j (-1)^{bit_q(j)} (psi_r[j]*psi_i[j^m] - psi_i[j]*psi_r[j^m])
// (verified on the 1-qubit case; equals R1's Psi-space form).
// ---------------------------------------------------------------------------
#define CMAC(AR, AI, UU, PRv, PIv)           \
    AR = fmaf((UU).x, (PRv), AR);            \
    AR = fmaf(-(UU).y, (PIv), AR);           \
    AI = fmaf((UU).x, (PIv), AI);            \
    AI = fmaf((UU).y, (PRv), AI);

__global__ __launch_bounds__(64, 1) void step_kernel(
    const float* __restrict__ sd, const float* __restrict__ pcf,
    const float* __restrict__ qp, const float2* __restrict__ um,
    float* __restrict__ out)
{
    __shared__ __align__(16) float2 sP[64];
    const int lane = threadIdx.x;
    const int b = blockIdx.x;

    int bitv[6];
#pragma unroll
    for (int i = 0; i < 6; i++) bitv[i] = (lane >> (5 - i)) & 1;
    int sflip[6];
    float sgnf[6];
#pragma unroll
    for (int q = 0; q < 6; q++) {
        sflip[q] = bitv[q] ? (int)0x80000000 : 0;
        sgnf[q]  = bitv[q] ? -1.f : 1.f;
    }

    // full U row for this lane: 64 float2 = 128 VGPRs (launch_bounds(64,1))
    float2 row[64];
#pragma unroll
    for (int c = 0; c < 64; c++) row[c] = um[(size_t)lane * 64 + c];

    // QSVT collapse: per-lane phase coefs + permuted product-state selects
    float A[6], sel[6];
    {
        int x1 = permf(lane), x2 = permf(x1), x3 = permf(x2), x4 = permf(x3);
#pragma unroll
        for (int i = 0; i < 6; i++) {
            float u0 = pcf[0] * PI_F * qp[0 * 6 + i];
            float u1 = pcf[1] * PI_F * qp[1 * 6 + i];
            float u2 = pcf[2] * PI_F * qp[2 * 6 + i];
            float u3 = pcf[3] * PI_F;
            float t1 = ((x1 >> (5 - i)) & 1) ? 0.5f : -0.5f;
            float t2 = ((x2 >> (5 - i)) & 1) ? 0.5f : -0.5f;
            float t3 = ((x3 >> (5 - i)) & 1) ? 0.5f : -0.5f;
            float t4 = ((x4 >> (5 - i)) & 1) ? 0.5f : -0.5f;
            A[i] = u3 * t1 + u2 * t2 + u1 * t3 + u0 * t4;
            sel[i] = (float)((x4 >> (5 - i)) & 1);
        }
    }

    // real 6-stage WHT butterfly: lane m ends with sum_j (-1)^{m.j} v_j
    auto b6 = [&](float v) -> float {
        float g;
        g = shxm<1>(v);  v = fmaf(sgnf[5], v, g);
        g = shxm<2>(v);  v = fmaf(sgnf[4], v, g);
        g = shxm<4>(v);  v = fmaf(sgnf[3], v, g);
        g = shxm<8>(v);  v = fmaf(sgnf[2], v, g);
        g = shxm<16>(v); v = fmaf(sgnf[1], v, g);
        g = shxm<32>(v); v = fmaf(sgnf[0], v, g);
        return v;
    };
    // complex 6-stage WHT butterfly
    auto b6c = [&](float& vr, float& vi) {
#define BSTG(M, SI) { float gr = shxm<M>(vr), gi = shxm<M>(vi); \
                      vr = fmaf(sgnf[SI], vr, gr); vi = fmaf(sgnf[SI], vi, gi); }
        BSTG(1, 5) BSTG(2, 4) BSTG(4, 3) BSTG(8, 2) BSTG(16, 1) BSTG(32, 0)
#undef BSTG
    };

    const float* sdb = sd + (size_t)b * SEQ * SDS;
    float* outb = out + (size_t)b * SEQ * 18;

    // hh = 0.5*h (the 0.5 of sincos(h/2) is folded into rec[6..17] by prep)
    float hh0 = 0.f, hh1 = 0.f, hh2 = 0.f, hh3 = 0.f, hh4 = 0.f, hh5 = 0.f;

    // ping-pong record fields: d[6], hc[6], hs[6]  (floats 0..17 of record)
    float bufA[18], bufB[18];
    {
        const float2* p2 = (const float2*)sdb;       // 216B stride: 8B aligned
#pragma unroll
        for (int k = 0; k < 9; k++) {
            float2 v = p2[k];
            bufA[2 * k] = v.x; bufA[2 * k + 1] = v.y;
        }
    }

    auto body = [&](float (&cur)[18], float (&nxt)[18], int t) {
        // prefetch next record (global loads stay in flight across the step:
        // wave_lds_sync drains lgkmcnt only)
        {
            int tn = (t + 1 < SEQ) ? t + 1 : t;
            const float2* rn2 = (const float2*)(sdb + (size_t)tn * SDS);
#pragma unroll
            for (int k = 0; k < 9; k++) {
                float2 v = rn2[k];
                nxt[2 * k] = v.x; nxt[2 * k + 1] = v.y;
            }
        }

        // ---- QSVT phase (h-independent) ----
        float phi = A[0]*cur[0] + A[1]*cur[1] + A[2]*cur[2]
                  + A[3]*cur[3] + A[4]*cur[4] + A[5]*cur[5];
        float sph, cph;
        __sincosf(phi, &sph, &cph);

        // ---- product state RY(h)|0..0>, pre-permuted via sel bits ----
        float ss0, cc0, ss1, cc1, ss2, cc2, ss3, cc3, ss4, cc4, ss5, cc5;
        __sincosf(hh0, &ss0, &cc0);
        __sincosf(hh1, &ss1, &cc1);
        __sincosf(hh2, &ss2, &cc2);
        __sincosf(hh3, &ss3, &cc3);
        __sincosf(hh4, &ss4, &cc4);
        __sincosf(hh5, &ss5, &cc5);
        float f0 = fmaf(sel[0], ss0 - cc0, cc0);
        float f1 = fmaf(sel[1], ss1 - cc1, cc1);
        float f2 = fmaf(sel[2], ss2 - cc2, cc2);
        float f3 = fmaf(sel[3], ss3 - cc3, cc3);
        float f4 = fmaf(sel[4], ss4 - cc4, cc4);
        float f5 = fmaf(sel[5], ss5 - cc5, cc5);
        float prod = ((f0 * f1) * (f2 * f3)) * (f4 * f5);
        float pr = prod * cph, pi = prod * sph;

        // ---- broadcast p through LDS (same-wave: lgkmcnt(0), no barrier) ----
        sP[lane] = make_float2(pr, pi);
        wave_lds_sync();

        // ---- full 64-column matvec, 4 accumulator pairs ----
        float a0r = 0.f, a0i = 0.f, a1r = 0.f, a1i = 0.f;
        float a2r = 0.f, a2i = 0.f, a3r = 0.f, a3i = 0.f;
#pragma unroll
        for (int c = 0; c < 64; c += 8) {
            float4 q0 = *reinterpret_cast<const float4*>(&sP[c + 0]);
            float4 q1 = *reinterpret_cast<const float4*>(&sP[c + 2]);
            float4 q2 = *reinterpret_cast<const float4*>(&sP[c + 4]);
            float4 q3 = *reinterpret_cast<const float4*>(&sP[c + 6]);
            CMAC(a0r, a0i, row[c + 0], q0.x, q0.y)
            CMAC(a1r, a1i, row[c + 1], q0.z, q0.w)
            CMAC(a2r, a2i, row[c + 2], q1.x, q1.y)
            CMAC(a3r, a3i, row[c + 3], q1.z, q1.w)
            CMAC(a0r, a0i, row[c + 4], q2.x, q2.y)
            CMAC(a1r, a1i, row[c + 5], q2.z, q2.w)
            CMAC(a2r, a2i, row[c + 6], q3.x, q3.y)
            CMAC(a3r, a3i, row[c + 7], q3.z, q3.w)
        }
        float re = (a0r + a1r) + (a2r + a3r);
        float im = (a0i + a1i) + (a2i + a3i);

        // ---- WHT-based Z,X (serial path) ----
        float P  = fmaf(re, re, im * im);
        float Wp = b6(P);                       // lane 32>>q holds Z_q
        float Rr = re, Ri = im;
        b6c(Rr, Ri);                            // Psi = WHT(psi')
        float Q  = fmaf(Rr, Rr, Ri * Ri) * 0.015625f;
        float Wq = b6(Q);                       // lane 32>>q holds X_q

        float Z0 = rdl<32>(Wp), Z1 = rdl<16>(Wp), Z2 = rdl<8>(Wp);
        float Z3 = rdl<4>(Wp),  Z4 = rdl<2>(Wp),  Z5 = rdl<1>(Wp);
        float X0 = rdl<32>(Wq), X1 = rdl<16>(Wq), X2 = rdl<8>(Wq);
        float X3 = rdl<4>(Wq),  X4 = rdl<2>(Wq),  X5 = rdl<1>(Wq);

        hh0 = cur[6]  * Z0 - cur[12] * X0;      // cur[6..17] pre-scaled by 0.5
        hh1 = cur[7]  * Z1 - cur[13] * X1;
        hh2 = cur[8]  * Z2 - cur[14] * X2;
        hh3 = cur[9]  * Z3 - cur[15] * X3;
        hh4 = cur[10] * Z4 - cur[16] * X4;
        hh5 = cur[11] * Z5 - cur[17] * X5;

        // ---- Y: 6 signed correlations on psi (off the serial path) ----
        float Yv[6];
        {
            float gr, gi;
            gr = shxm<32>(re); gi = shxm<32>(im);
            Yv[0] = redsum64(xorf(fmaf(re, gi, -(im * gr)), sflip[0]));
            gr = shxm<16>(re); gi = shxm<16>(im);
            Yv[1] = redsum64(xorf(fmaf(re, gi, -(im * gr)), sflip[1]));
            gr = shxm<8>(re);  gi = shxm<8>(im);
            Yv[2] = redsum64(xorf(fmaf(re, gi, -(im * gr)), sflip[2]));
            gr = shxm<4>(re);  gi = shxm<4>(im);
            Yv[3] = redsum64(xorf(fmaf(re, gi, -(im * gr)), sflip[3]));
            gr = shxm<2>(re);  gi = shxm<2>(im);
            Yv[4] = redsum64(xorf(fmaf(re, gi, -(im * gr)), sflip[4]));
            gr = shxm<1>(re);  gi = shxm<1>(im);
            Yv[5] = redsum64(xorf(fmaf(re, gi, -(im * gr)), sflip[5]));
        }

        // ---- store raw Z/X/Y (finalized by post_kernel) ----
        if (lane == 0) {
            float2* o2 = (float2*)(outb + (size_t)t * 18);
            o2[0] = make_float2(Z0, Z1); o2[1] = make_float2(Z2, Z3);
            o2[2] = make_float2(Z4, Z5); o2[3] = make_float2(X0, X1);
            o2[4] = make_float2(X2, X3); o2[5] = make_float2(X4, X5);
            o2[6] = make_float2(Yv[0], Yv[1]);
            o2[7] = make_float2(Yv[2], Yv[3]);
            o2[8] = make_float2(Yv[4], Yv[5]);
        }
    };

    for (int t = 0; t < SEQ; t += 2) {
        body(bufA, bufB, t);
        body(bufB, bufA, t + 1);
    }
}
#undef CMAC

// ---------------------------------------------------------------------------
// post_kernel: finalize outputs (in place over the raw Z/X/Y step_kernel
// wrote into `out`). rec holds hc=0.5*cos, hs=0.5*sin and doubled Cc on the
// px/h' rows, so the formulas below are value-identical to the original.
// ---------------------------------------------------------------------------
__global__ __launch_bounds__(256) void post_kernel(
    const float* __restrict__ sd, float* __restrict__ out)
{
    int gid = blockIdx.x * blockDim.x + threadIdx.x;
    if (gid >= BATCH * SEQ) return;
    const float* rec = sd + (size_t)gid * SDS;
    float* o = out + (size_t)gid * 18;

    float zxy[18];
    {
        const float2* o2 = (const float2*)o;
#pragma unroll
        for (int k = 0; k < 9; k++) {
            float2 v = o2[k];
            zxy[2 * k] = v.x; zxy[2 * k + 1] = v.y;
        }
    }
    float r[54];
    {
        const float2* r2 = (const float2*)rec;
#pragma unroll
        for (int k = 3; k < 27; k++) {       // floats 6..53 (hc,hs,Cc,term)
            float2 v = r2[k];
            r[2 * k] = v.x; r[2 * k + 1] = v.y;
        }
    }
    float res[18];
#pragma unroll
    for (int q = 0; q < 6; q++) {
        float Z = zxy[q], X = zxy[6 + q], Y = zxy[12 + q];
        float c = r[6 + q], s = r[12 + q];   // = 0.5*cos, 0.5*sin
        float px = c * X + s * Z;            // = 0.5*(cos*X + sin*Z)
        float hq = c * Z - s * X;            // = 0.5*(cos*Z - sin*X)
        res[q]      = fmaf(r[18 + q], px, r[36 + q]);   // r18 doubled in prep
        res[6 + q]  = fmaf(r[24 + q], Y,  r[42 + q]);   // unscaled
        res[12 + q] = fmaf(r[30 + q], hq, r[48 + q]);   // r30 doubled in prep
    }
    float2* ow = (float2*)o;
#pragma unroll
    for (int k = 0; k < 9; k++) ow[k] = make_float2(res[2 * k], res[2 * k + 1]);
}

// ---------------------------------------------------------------------------
extern "C" void kernel_launch(void* const* d_in, const int* in_sizes, int n_in,
                              void* d_out, int out_size, void* d_ws, size_t ws_size,
                              hipStream_t stream) {
    const float* angles = (const float*)d_in[0];
    const float* Wx     = (const float*)d_in[1];
    const float* Wdt    = (const float*)d_in[2];
    const float* bdt    = (const float*)d_in[3];
    const float* pc     = (const float*)d_in[4];
    const float* qp     = (const float*)d_in[5];
    const float* cp     = (const float*)d_in[6];
    const float* D      = (const float*)d_in[7];
    const float* Wc     = (const float*)d_in[8];
    float* sd  = (float*)d_ws;                                // 28.3 MB
    float2* um = (float2*)(sd + (size_t)BATCH * SEQ * SDS);   // +32 KB
    float* out = (float*)d_out;

    umat_kernel<<<64, 64, 0, stream>>>(cp, um);
    prep_kernel<<<(BATCH * SEQ) / 256, 256, 0, stream>>>(angles, Wx, Wdt, bdt, D, Wc, sd);
    step_kernel<<<BATCH, 64, 0, stream>>>(sd, pc, qp, um, out);
    post_kernel<<<(BATCH * SEQ) / 256, 256, 0, stream>>>(sd, out);
}

// Round 4
// 708.291 us; speedup vs baseline: 1.3608x; 1.3608x over previous
//
#include <hip/hip_runtime.h>
#include <math.h>

#define BATCH 256
#define SEQ 512
#define SDS 54            // floats per (b,t) record: dt[6] hc[6] hs[6] Cc[18] term[18]
#define PI_F 3.14159265358979323846f
#define INV2PI_F 0.15915494309189535f

// ---- cross-lane helpers (ALL VALU — no LDS pipe) ---------------------------
template<int CTRL>
__device__ __forceinline__ float fdpp(float v) {
    return __int_as_float(__builtin_amdgcn_mov_dpp(__float_as_int(v), CTRL, 0xF, 0xF, true));
}
template<int L>
__device__ __forceinline__ float rdl(float v) {
    return __int_as_float(__builtin_amdgcn_readlane(__float_as_int(v), L));
}
__device__ __forceinline__ float rdlv(float v, int l) {
    return __int_as_float(__builtin_amdgcn_readlane(__float_as_int(v), l));
}
// xor1 / xor2 / xor4 / xor8 via DPP (quad_perm, compose, row_ror)
__device__ __forceinline__ float x1f(float v) { return fdpp<0xB1>(v); }
__device__ __forceinline__ float x2f(float v) { return fdpp<0x4E>(v); }
__device__ __forceinline__ float x4f(float v) { return fdpp<0x141>(fdpp<0x1B>(v)); } // xor7∘xor3
__device__ __forceinline__ float x8f(float v) { return fdpp<0x128>(v); }             // ror8≡xor8 in row16
// sum with xor-16 / xor-32 partner, direction-proof: r[0]+r[1] == v[l]+v[l^m]
// in either swap convention of v_permlane*_swap_b32.
#if __has_builtin(__builtin_amdgcn_permlane16_swap)
__device__ __forceinline__ float sum16(float v) {
    typedef unsigned int u2v __attribute__((ext_vector_type(2)));
    u2v r = __builtin_amdgcn_permlane16_swap(__float_as_uint(v), __float_as_uint(v), false, false);
    return __uint_as_float(r[0]) + __uint_as_float(r[1]);
}
#else
__device__ __forceinline__ float sum16(float v) {
    return v + __int_as_float(__builtin_amdgcn_ds_swizzle(__float_as_int(v), (16 << 10) | 0x1F));
}
#endif
#if __has_builtin(__builtin_amdgcn_permlane32_swap)
__device__ __forceinline__ float sum32(float v) {
    typedef unsigned int u2v __attribute__((ext_vector_type(2)));
    u2v r = __builtin_amdgcn_permlane32_swap(__float_as_uint(v), __float_as_uint(v), false, false);
    return __uint_as_float(r[0]) + __uint_as_float(r[1]);
}
#else
__device__ __forceinline__ float sum32(float v) { return v + __shfl_xor(v, 32, 64); }
#endif
// full 64-lane sum, uniform in every lane, fully VALU
__device__ __forceinline__ float redsum64(float v) {
    v += fdpp<0x128>(v);
    v += fdpp<0x124>(v);
    v += fdpp<0x122>(v);
    v += fdpp<0x121>(v);           // every lane: its row16 sum
    v = sum16(v);                  // + partner row
    v = sum32(v);                  // + other half
    return v;
}
__device__ __forceinline__ float xorf(float v, int m) {
    return __int_as_float(__float_as_int(v) ^ m);
}
// Workgroup barrier WITHOUT vmcnt drain: LDS-only visibility.
// 0xC07F = vmcnt(63) expcnt(7) lgkmcnt(0) in gfx9 encoding.
__device__ __forceinline__ void wg_barrier_lds() {
    __builtin_amdgcn_sched_barrier(0);
    __builtin_amdgcn_s_waitcnt(0xC07F);
    __builtin_amdgcn_s_barrier();
    __builtin_amdgcn_sched_barrier(0);
}
// QSVT per-degree CNOT-block permutation (GF(2)-linear) — verified R1-R6
__device__ __forceinline__ int permf(int x) {
    const int cs[11] = {0,1,2,3,4,5,5,4,3,2,1};
    const int ts[11] = {1,2,3,4,5,0,4,3,2,1,0};
#pragma unroll
    for (int k = 10; k >= 0; k--) {
        int cb = (x >> (5 - cs[k])) & 1;
        x ^= cb << (5 - ts[k]);
    }
    return x;
}
__device__ __forceinline__ void cmul4(const float* c,
    float vr, float vi, float ar, float ai, float br, float bi, float cr, float ci,
    float& nr, float& ni) {
    nr = c[0]*vr - c[1]*vi + c[2]*ar - c[3]*ai + c[4]*br - c[5]*bi + c[6]*cr - c[7]*ci;
    ni = c[0]*vi + c[1]*vr + c[2]*ai + c[3]*ar + c[4]*bi + c[5]*br + c[6]*ci + c[7]*cr;
}
__device__ __forceinline__ void ringapply(const float* rc,
    float vr, float vi, float br, float bi, float cr, float ci, float dr, float di,
    float& nr, float& ni) {
    nr = rc[0]*vr - rc[1]*bi - rc[2]*ci + rc[3]*dr;
    ni = rc[0]*vi + rc[1]*br + rc[2]*cr + rc[3]*di;
}

// ---------------------------------------------------------------------------
// prep_kernel: stores 0.5*cos, 0.5*sin in rec[6..17] (folds the 0.5 of
// sincos(h/2)), compensated by 2x on Cc rows 0-5 and 12-17.
// ---------------------------------------------------------------------------
__global__ __launch_bounds__(256) void prep_kernel(
    const float* __restrict__ angles, const float* __restrict__ Wx,
    const float* __restrict__ Wdt, const float* __restrict__ bdt,
    const float* __restrict__ D, const float* __restrict__ Wc,
    float* __restrict__ sd)
{
    int gid = blockIdx.x * blockDim.x + threadIdx.x;
    if (gid >= BATCH * SEQ) return;
    const float* a = angles + (size_t)gid * 6;
    float ang[6];
#pragma unroll
    for (int i = 0; i < 6; i++) ang[i] = a[i];
    float dtr[3];
#pragma unroll
    for (int r = 0; r < 3; r++) {
        float s = 0.f;
#pragma unroll
        for (int k = 0; k < 6; k++) s += ang[k] * Wx[r * 6 + k];
        dtr[r] = s;
    }
    float* rec = sd + (size_t)gid * SDS;
    float dtv[6];
#pragma unroll
    for (int i = 0; i < 6; i++) {
        float x = bdt[i];
#pragma unroll
        for (int r = 0; r < 3; r++) x += dtr[r] * Wdt[i * 3 + r];
        float sp = (x > 15.f) ? x : log1pf(expf(x));
        dtv[i] = tanhf(sp) * PI_F;
        rec[i] = dtv[i];
        float th = ang[i] * dtv[i];
        rec[6 + i]  = 0.5f * cosf(th);
        rec[12 + i] = 0.5f * sinf(th);
    }
    float C[6];
#pragma unroll
    for (int i = 0; i < 6; i++) {
        float s = 0.f;
#pragma unroll
        for (int k = 0; k < 6; k++) s += ang[k] * Wx[(9 + i) * 6 + k];
        C[i] = s;
    }
#pragma unroll
    for (int j = 0; j < 18; j++) {
        float s = 0.f;
#pragma unroll
        for (int i = 0; i < 6; i++) s += C[i] * Wc[j * 6 + i];
        rec[18 + j] = (j < 6 || j >= 12) ? 2.f * s : s;
        rec[36 + j] = D[j] * ang[j % 6];
    }
}

// ---------------------------------------------------------------------------
// umat_kernel: U[a][col] for the fixed 2-layer ansatz (R2-verified gate chain).
// ---------------------------------------------------------------------------
__global__ __launch_bounds__(64) void umat_kernel(const float* __restrict__ cp,
                                                  float2* __restrict__ um)
{
    const int lane = threadIdx.x;
    const int col = blockIdx.x;
    int bitv[6];
#pragma unroll
    for (int i = 0; i < 6; i++) bitv[i] = (lane >> (5 - i)) & 1;

    float qc[2][3][8], rc[2][6][4];
#pragma unroll
    for (int l = 0; l < 2; l++) {
        float g00r[6], g00i[6], g01r[6], g01i[6], g10r[6], g10i[6], g11r[6], g11i[6];
#pragma unroll
        for (int i = 0; i < 6; i++) {
            float ax = cp[l * 30 + i * 3 + 0];
            float ay = cp[l * 30 + i * 3 + 1];
            float az = cp[l * 30 + i * 3 + 2];
            float ca = cosf(0.5f * ax), sa = sinf(0.5f * ax);
            float cb = cosf(0.5f * ay), sb = sinf(0.5f * ay);
            float cg = cosf(0.5f * az), sg = sinf(0.5f * az);
            float m00r = cb * ca, m00i =  sb * sa;
            float m01r = -sb * ca, m01i = -cb * sa;
            float m10r =  sb * ca, m10i = -cb * sa;
            float m11r =  cb * ca, m11i = -sb * sa;
            g00r[i] = cg * m00r + sg * m00i; g00i[i] = cg * m00i - sg * m00r;
            g01r[i] = cg * m01r + sg * m01i; g01i[i] = cg * m01i - sg * m01r;
            g10r[i] = cg * m10r - sg * m10i; g10i[i] = cg * m10i + sg * m10r;
            g11r[i] = cg * m11r - sg * m11i; g11i[i] = cg * m11i + sg * m11r;
        }
#pragma unroll
        for (int pp = 0; pp < 3; pp++) {
            int aq = 2 * pp, bq = 2 * pp + 1;
            float dar = bitv[aq] ? g11r[aq] : g00r[aq], dai = bitv[aq] ? g11i[aq] : g00i[aq];
            float oar = bitv[aq] ? g10r[aq] : g01r[aq], oai = bitv[aq] ? g10i[aq] : g01i[aq];
            float dbr = bitv[bq] ? g11r[bq] : g00r[bq], dbi = bitv[bq] ? g11i[bq] : g00i[bq];
            float obr = bitv[bq] ? g10r[bq] : g01r[bq], obi = bitv[bq] ? g10i[bq] : g01i[bq];
            qc[l][pp][0] = dar * dbr - dai * dbi;  qc[l][pp][1] = dar * dbi + dai * dbr;
            qc[l][pp][2] = oar * dbr - oai * dbi;  qc[l][pp][3] = oar * dbi + oai * dbr;
            qc[l][pp][4] = dar * obr - dai * obi;  qc[l][pp][5] = dar * obi + dai * obr;
            qc[l][pp][6] = oar * obr - oai * obi;  qc[l][pp][7] = oar * obi + oai * obr;
        }
        const int Aq[6] = {0, 2, 4, 5, 3, 1};
        const int Bq[6] = {1, 3, 5, 4, 2, 0};
#pragma unroll
        for (int o = 0; o < 6; o++) {
            float tha = (o < 3) ? cp[l * 30 + 18 + 2 * o]     : cp[l * 30 + 24 + 2 * (o - 3)];
            float thb = (o < 3) ? cp[l * 30 + 18 + 2 * o + 1] : cp[l * 30 + 24 + 2 * (o - 3) + 1];
            float ca = cosf(0.5f * tha), sa = sinf(0.5f * tha);
            float cb = cosf(0.5f * thb), sb = sinf(0.5f * thb);
            int ba = bitv[Aq[o]], bb = bitv[Bq[o]];
            float mx0 = ba ? ca : 1.f, sae = ba ? sa : 0.f;
            float ny0 = bb ? cb : 1.f, sbe = bb ? sb : 0.f;
            rc[l][o][0] = ny0 * mx0; rc[l][o][1] = -ny0 * sae;
            rc[l][o][2] = -mx0 * sbe; rc[l][o][3] = -sae * sbe;
        }
    }

    float re = (lane == col) ? 1.f : 0.f;
    float im = 0.f;
    auto p1q = [&](int mi, int mj, const float* c) {
        float ar = __shfl_xor(re, mi, 64), ai = __shfl_xor(im, mi, 64);
        float br = __shfl_xor(re, mj, 64), bi = __shfl_xor(im, mj, 64);
        float cr = __shfl_xor(re, mi | mj, 64), ci = __shfl_xor(im, mi | mj, 64);
        float nr, ni;
        cmul4(c, re, im, ar, ai, br, bi, cr, ci, nr, ni);
        re = nr; im = ni;
    };
    auto rng = [&](int mb, int mc, const float* c) {
        float br = __shfl_xor(re, mb, 64), bi = __shfl_xor(im, mb, 64);
        float cr = __shfl_xor(re, mc, 64), ci = __shfl_xor(im, mc, 64);
        float dr = __shfl_xor(re, mb | mc, 64), di = __shfl_xor(im, mb | mc, 64);
        float nr, ni;
        ringapply(c, re, im, br, bi, cr, ci, dr, di, nr, ni);
        re = nr; im = ni;
    };
#pragma unroll
    for (int l = 0; l < 2; l++) {
        p1q(32, 16, qc[l][0]);
        p1q(8, 4, qc[l][1]);
        p1q(2, 1, qc[l][2]);
        rng(16, 8, rc[l][0]);
        rng(4, 2, rc[l][1]);
        rng(1, 32, rc[l][2]);
        rng(2, 4, rc[l][3]);
        rng(8, 16, rc[l][4]);
        rng(32, 1, rc[l][5]);
    }
    um[(size_t)lane * 64 + col] = make_float2(re, im);
}

// ---------------------------------------------------------------------------
// step_kernel v4: 4 waves/element, ONE barrier/step, critical path VALU-only.
// The only LDS on the path: partials ds_write + lgkm wait + barrier + 4 reads.
// Z via b6(P) WHT butterfly (DPP + permlane-sum stages); X via 6 direct
// correlations X_q = redsum64(re*g_r + im*g_i), g = psi[l^m_q]; Y (output
// only) reuses the same shuffles, split 2-per-wave on waves 1-3.
// Records prefetched 2 ahead (3 rotating buffers); the h-independent QSVT
// phase sincos is precomputed one step early. Raw sin/cos (v_sin/v_cos,
// args in revolutions; phi fract-reduced exactly).
// ---------------------------------------------------------------------------
#define CMACR(AR, AI, UU, SR, SI)            \
    AR = fmaf((UU).x, (SR), AR);             \
    AR = fmaf(-(UU).y, (SI), AR);            \
    AI = fmaf((UU).x, (SI), AI);             \
    AI = fmaf((UU).y, (SR), AI);

__global__ __launch_bounds__(256, 1) void step_kernel(
    const float* __restrict__ sd, const float* __restrict__ pcf,
    const float* __restrict__ qp, const float2* __restrict__ um,
    float* __restrict__ out)
{
    __shared__ float2 sPart[2][4][64];
    const int tid = threadIdx.x;
    const int wave = tid >> 6;
    const int lane = tid & 63;
    const int b = blockIdx.x;

    int bitv[6];
#pragma unroll
    for (int i = 0; i < 6; i++) bitv[i] = (lane >> (5 - i)) & 1;
    int sflip[6];
    float sgnf[6];
#pragma unroll
    for (int q = 0; q < 6; q++) {
        sflip[q] = bitv[q] ? (int)0x80000000 : 0;
        sgnf[q]  = bitv[q] ? -1.f : 1.f;
    }
    const float w0 = bitv[0] ? -2.f : 0.f;   // permlane-sum butterfly weights
    const float w1 = bitv[1] ? -2.f : 0.f;

    // U column-chunk rows: wave w owns columns [16w, 16w+16)
    const int jbase = wave * 16;
    float2 row[16];
#pragma unroll
    for (int jj = 0; jj < 16; jj++) row[jj] = um[(size_t)lane * 64 + jbase + jj];

    // QSVT collapse: per-lane phase coefs + permuted product-state selects
    float A[6], sel[6];
    {
        int x1 = permf(lane), x2 = permf(x1), x3 = permf(x2), x4 = permf(x3);
#pragma unroll
        for (int i = 0; i < 6; i++) {
            float u0 = pcf[0] * PI_F * qp[0 * 6 + i];
            float u1 = pcf[1] * PI_F * qp[1 * 6 + i];
            float u2 = pcf[2] * PI_F * qp[2 * 6 + i];
            float u3 = pcf[3] * PI_F;
            float t1 = ((x1 >> (5 - i)) & 1) ? 0.5f : -0.5f;
            float t2 = ((x2 >> (5 - i)) & 1) ? 0.5f : -0.5f;
            float t3 = ((x3 >> (5 - i)) & 1) ? 0.5f : -0.5f;
            float t4 = ((x4 >> (5 - i)) & 1) ? 0.5f : -0.5f;
            A[i] = u3 * t1 + u2 * t2 + u1 * t3 + u0 * t4;
            sel[i] = (float)((x4 >> (5 - i)) & 1);
        }
    }

    // 6-stage WHT butterfly, fully VALU (DPP + permlane-sum for 16/32):
    // lane m ends with sum_j (-1)^{m.j} v_j
    auto b6 = [&](float v) -> float {
        float g;
        g = x1f(v); v = fmaf(sgnf[5], v, g);
        g = x2f(v); v = fmaf(sgnf[4], v, g);
        g = x4f(v); v = fmaf(sgnf[3], v, g);
        g = x8f(v); v = fmaf(sgnf[2], v, g);
        v = fmaf(w1, v, sum16(v));    // bit1: v' = (v+g) - 2v = g - v; else g + v
        v = fmaf(w0, v, sum32(v));
        return v;
    };

    const float* sdb = sd + (size_t)b * SEQ * SDS;
    float* outb = out + (size_t)b * SEQ * 18;

    // hh = 0.5*h (the 0.5 of sincos(h/2) is folded into rec[6..17] by prep)
    float hh0 = 0.f, hh1 = 0.f, hh2 = 0.f, hh3 = 0.f, hh4 = 0.f, hh5 = 0.f;

    // 3 rotating record buffers (2-ahead prefetch): d[6], hc[6], hs[6]
    float buf0[18], buf1[18], buf2[18];
    auto ldrec = [&](float (&dst)[18], int t) {
        const float2* p2 = (const float2*)(sdb + (size_t)t * SDS);
#pragma unroll
        for (int k = 0; k < 9; k++) {
            float2 v = p2[k];
            dst[2 * k] = v.x; dst[2 * k + 1] = v.y;
        }
    };
    ldrec(buf0, 0);
    ldrec(buf1, 1);

    // phase sincos for the step about to execute (precomputed from its record)
    float sphC, cphC;
    {
        float phi = A[0]*buf0[0] + A[1]*buf0[1] + A[2]*buf0[2]
                  + A[3]*buf0[3] + A[4]*buf0[4] + A[5]*buf0[5];
        float u = phi * INV2PI_F;
        u = u - floorf(u);                       // exact periodic reduction
        sphC = __builtin_amdgcn_sinf(u);
        cphC = __builtin_amdgcn_cosf(u);
    }

    auto body = [&](float (&cur)[18], float (&nxt)[18], float (&far)[18], int t) {
        const int pp = t & 1;
        // prefetch record t+2 (vmem stays in flight; barrier drains lgkm only)
        ldrec(far, (t + 2 < SEQ) ? t + 2 : SEQ - 1);

        // ---- product state RY(h)|0..0>, pre-permuted via sel bits ----
        // (raw v_sin/v_cos: |hh| <= ~1 rad -> |rev| <= 0.17, in range)
        float ss0 = __builtin_amdgcn_sinf(hh0 * INV2PI_F), cc0 = __builtin_amdgcn_cosf(hh0 * INV2PI_F);
        float ss1 = __builtin_amdgcn_sinf(hh1 * INV2PI_F), cc1 = __builtin_amdgcn_cosf(hh1 * INV2PI_F);
        float ss2 = __builtin_amdgcn_sinf(hh2 * INV2PI_F), cc2 = __builtin_amdgcn_cosf(hh2 * INV2PI_F);
        float ss3 = __builtin_amdgcn_sinf(hh3 * INV2PI_F), cc3 = __builtin_amdgcn_cosf(hh3 * INV2PI_F);
        float ss4 = __builtin_amdgcn_sinf(hh4 * INV2PI_F), cc4 = __builtin_amdgcn_cosf(hh4 * INV2PI_F);
        float ss5 = __builtin_amdgcn_sinf(hh5 * INV2PI_F), cc5 = __builtin_amdgcn_cosf(hh5 * INV2PI_F);
        float f0 = fmaf(sel[0], ss0 - cc0, cc0);
        float f1 = fmaf(sel[1], ss1 - cc1, cc1);
        float f2 = fmaf(sel[2], ss2 - cc2, cc2);
        float f3 = fmaf(sel[3], ss3 - cc3, cc3);
        float f4 = fmaf(sel[4], ss4 - cc4, cc4);
        float f5 = fmaf(sel[5], ss5 - cc5, cc5);
        float prod = ((f0 * f1) * (f2 * f3)) * (f4 * f5);
        float pr = prod * cphC, pi = prod * sphC;

        // ---- precompute next step's phase from nxt (loaded 1 body ago) ----
        {
            float phi = A[0]*nxt[0] + A[1]*nxt[1] + A[2]*nxt[2]
                      + A[3]*nxt[3] + A[4]*nxt[4] + A[5]*nxt[5];
            float u = phi * INV2PI_F;
            u = u - floorf(u);
            sphC = __builtin_amdgcn_sinf(u);
            cphC = __builtin_amdgcn_cosf(u);
        }

        // ---- partial matvec over this wave's 16 columns (readlane bcast) ----
        float ar0 = 0.f, ai0 = 0.f, ar1 = 0.f, ai1 = 0.f;
#pragma unroll
        for (int jj = 0; jj < 16; jj += 2) {
            float sr0 = rdlv(pr, jbase + jj);
            float si0 = rdlv(pi, jbase + jj);
            float sr1 = rdlv(pr, jbase + jj + 1);
            float si1 = rdlv(pi, jbase + jj + 1);
            CMACR(ar0, ai0, row[jj], sr0, si0)
            CMACR(ar1, ai1, row[jj + 1], sr1, si1)
        }
        sPart[pp][wave][lane] = make_float2(ar0 + ar1, ai0 + ai1);
        wg_barrier_lds();   // the ONLY barrier per step
        float2 q0v = sPart[pp][0][lane], q1v = sPart[pp][1][lane];
        float2 q2v = sPart[pp][2][lane], q3v = sPart[pp][3][lane];
        float re = (q0v.x + q1v.x) + (q2v.x + q3v.x);
        float im = (q0v.y + q1v.y) + (q2v.y + q3v.y);

        // ---- Z via WHT butterfly (VALU-only) ----
        float P  = fmaf(re, re, im * im);
        float Wp = b6(P);                       // lane 32>>q holds Z_q
        float Z0 = rdl<32>(Wp), Z1 = rdl<16>(Wp), Z2 = rdl<8>(Wp);
        float Z3 = rdl<4>(Wp),  Z4 = rdl<2>(Wp),  Z5 = rdl<1>(Wp);

        // ---- partner states for all 6 masks (VALU-only) ----
        float g32r = sum32(re) - re, g32i = sum32(im) - im;   // xor32
        float g16r = sum16(re) - re, g16i = sum16(im) - im;   // xor16
        float g8r  = x8f(re),        g8i  = x8f(im);
        float g4r  = x4f(re),        g4i  = x4f(im);
        float g2r  = x2f(re),        g2i  = x2f(im);
        float g1r  = x1f(re),        g1i  = x1f(im);

        // ---- X via direct correlations (uniform results, no readout) ----
        float X0 = redsum64(fmaf(re, g32r, im * g32i));
        float X1 = redsum64(fmaf(re, g16r, im * g16i));
        float X2 = redsum64(fmaf(re, g8r,  im * g8i));
        float X3 = redsum64(fmaf(re, g4r,  im * g4i));
        float X4 = redsum64(fmaf(re, g2r,  im * g2i));
        float X5 = redsum64(fmaf(re, g1r,  im * g1i));

        // ---- h recurrence (cur[6..17] pre-scaled by 0.5) ----
        hh0 = cur[6]  * Z0 - cur[12] * X0;
        hh1 = cur[7]  * Z1 - cur[13] * X1;
        hh2 = cur[8]  * Z2 - cur[14] * X2;
        hh3 = cur[9]  * Z3 - cur[15] * X3;
        hh4 = cur[10] * Z4 - cur[16] * X4;
        hh5 = cur[11] * Z5 - cur[17] * X5;

        // ---- Y (output only): reuse shuffles, split 2-per-wave on waves 1-3
        float* o = outb + (size_t)t * 18;
        if (wave == 0) {
            if (lane == 0) {
                float2* o2 = (float2*)o;
                o2[0] = make_float2(Z0, Z1); o2[1] = make_float2(Z2, Z3);
                o2[2] = make_float2(Z4, Z5); o2[3] = make_float2(X0, X1);
                o2[4] = make_float2(X2, X3); o2[5] = make_float2(X4, X5);
            }
        } else if (wave == 1) {
            float Y0 = redsum64(xorf(fmaf(re, g32i, -(im * g32r)), sflip[0]));
            float Y1 = redsum64(xorf(fmaf(re, g16i, -(im * g16r)), sflip[1]));
            if (lane == 0) ((float2*)(o + 12))[0] = make_float2(Y0, Y1);
        } else if (wave == 2) {
            float Y2 = redsum64(xorf(fmaf(re, g8i, -(im * g8r)), sflip[2]));
            float Y3 = redsum64(xorf(fmaf(re, g4i, -(im * g4r)), sflip[3]));
            if (lane == 0) ((float2*)(o + 14))[0] = make_float2(Y2, Y3);
        } else {
            float Y4 = redsum64(xorf(fmaf(re, g2i, -(im * g2r)), sflip[4]));
            float Y5 = redsum64(xorf(fmaf(re, g1i, -(im * g1r)), sflip[5]));
            if (lane == 0) ((float2*)(o + 16))[0] = make_float2(Y4, Y5);
        }
    };

    for (int t = 0; t < 510; t += 3) {
        body(buf0, buf1, buf2, t);
        body(buf1, buf2, buf0, t + 1);
        body(buf2, buf0, buf1, t + 2);
    }
    body(buf0, buf1, buf2, 510);
    body(buf1, buf2, buf0, 511);
}
#undef CMACR

// ---------------------------------------------------------------------------
// post_kernel: finalize outputs in place over the raw Z/X/Y. rec holds
// hc=0.5*cos, hs=0.5*sin and doubled Cc on the px/h' rows — value-identical
// to the original formulas.
// ---------------------------------------------------------------------------
__global__ __launch_bounds__(256) void post_kernel(
    const float* __restrict__ sd, float* __restrict__ out)
{
    int gid = blockIdx.x * blockDim.x + threadIdx.x;
    if (gid >= BATCH * SEQ) return;
    const float* rec = sd + (size_t)gid * SDS;
    float* o = out + (size_t)gid * 18;

    float zxy[18];
    {
        const float2* o2 = (const float2*)o;
#pragma unroll
        for (int k = 0; k < 9; k++) {
            float2 v = o2[k];
            zxy[2 * k] = v.x; zxy[2 * k + 1] = v.y;
        }
    }
    float r[54];
    {
        const float2* r2 = (const float2*)rec;
#pragma unroll
        for (int k = 3; k < 27; k++) {       // floats 6..53 (hc,hs,Cc,term)
            float2 v = r2[k];
            r[2 * k] = v.x; r[2 * k + 1] = v.y;
        }
    }
    float res[18];
#pragma unroll
    for (int q = 0; q < 6; q++) {
        float Z = zxy[q], X = zxy[6 + q], Y = zxy[12 + q];
        float c = r[6 + q], s = r[12 + q];   // = 0.5*cos, 0.5*sin
        float px = c * X + s * Z;
        float hq = c * Z - s * X;
        res[q]      = fmaf(r[18 + q], px, r[36 + q]);
        res[6 + q]  = fmaf(r[24 + q], Y,  r[42 + q]);
        res[12 + q] = fmaf(r[30 + q], hq, r[48 + q]);
    }
    float2* ow = (float2*)o;
#pragma unroll
    for (int k = 0; k < 9; k++) ow[k] = make_float2(res[2 * k], res[2 * k + 1]);
}

// ---------------------------------------------------------------------------
extern "C" void kernel_launch(void* const* d_in, const int* in_sizes, int n_in,
                              void* d_out, int out_size, void* d_ws, size_t ws_size,
                              hipStream_t stream) {
    const float* angles = (const float*)d_in[0];
    const float* Wx     = (const float*)d_in[1];
    const float* Wdt    = (const float*)d_in[2];
    const float* bdt    = (const float*)d_in[3];
    const float* pc     = (const float*)d_in[4];
    const float* qp     = (const float*)d_in[5];
    const float* cp     = (const float*)d_in[6];
    const float* D      = (const float*)d_in[7];
    const float* Wc     = (const float*)d_in[8];
    float* sd  = (float*)d_ws;                                // 28.3 MB
    float2* um = (float2*)(sd + (size_t)BATCH * SEQ * SDS);   // +32 KB
    float* out = (float*)d_out;

    umat_kernel<<<64, 64, 0, stream>>>(cp, um);
    prep_kernel<<<(BATCH * SEQ) / 256, 256, 0, stream>>>(angles, Wx, Wdt, bdt, D, Wc, sd);
    step_kernel<<<BATCH, 256, 0, stream>>>(sd, pc, qp, um, out);
    post_kernel<<<(BATCH * SEQ) / 256, 256, 0, stream>>>(sd, out);
}